// Round 1
// baseline (947.603 us; speedup 1.0000x reference)
//
#include <hip/hip_runtime.h>

#define DIM 64
#define SCAN_CHUNK 1024

// ---------------- CSR build ----------------

__global__ __launch_bounds__(256) void k_count(const int* __restrict__ dst, int E,
                                               int* __restrict__ cnt) {
    int i = blockIdx.x * blockDim.x + threadIdx.x;
    if (i < E) atomicAdd(&cnt[dst[i]], 1);
}

__global__ __launch_bounds__(256) void k_dinv(const int* __restrict__ cnt, int N,
                                              float* __restrict__ dinv) {
    int i = blockIdx.x * blockDim.x + threadIdx.x;
    if (i < N) dinv[i] = rsqrtf((float)(cnt[i] + 1));  // +1 self-loop; deg >= 1 always
}

__global__ __launch_bounds__(256) void k_scan1(const int* __restrict__ cnt, int N,
                                               int* __restrict__ partial) {
    __shared__ int sdata[256];
    int base = blockIdx.x * SCAN_CHUNK;
    int t = threadIdx.x;
    int s = 0;
    for (int j = 0; j < 4; ++j) {
        int idx = base + t + j * 256;
        if (idx < N) s += cnt[idx];
    }
    sdata[t] = s;
    __syncthreads();
    for (int off = 128; off > 0; off >>= 1) {
        if (t < off) sdata[t] += sdata[t + off];
        __syncthreads();
    }
    if (t == 0) partial[blockIdx.x] = sdata[0];
}

__global__ void k_scan2(int* __restrict__ partial, int nblk,
                        int* __restrict__ row_ptr, int N, int E) {
    if (threadIdx.x == 0) {
        int run = 0;
        for (int i = 0; i < nblk; ++i) { int v = partial[i]; partial[i] = run; run += v; }
        row_ptr[N] = E;
    }
}

__global__ __launch_bounds__(256) void k_scan3(const int* __restrict__ cnt, int N,
                                               const int* __restrict__ partial,
                                               int* __restrict__ row_ptr) {
    __shared__ int sdata[256];
    int base = blockIdx.x * SCAN_CHUNK;
    int t = threadIdx.x;
    int idx0 = base + t * 4;
    int v[4]; int s = 0;
    for (int j = 0; j < 4; ++j) { int idx = idx0 + j; v[j] = (idx < N) ? cnt[idx] : 0; s += v[j]; }
    sdata[t] = s;
    __syncthreads();
    for (int off = 1; off < 256; off <<= 1) {
        int tmp = (t >= off) ? sdata[t - off] : 0;
        __syncthreads();
        if (t >= off) sdata[t] += tmp;
        __syncthreads();
    }
    int excl = sdata[t] - s;
    int baseoff = partial[blockIdx.x] + excl;
    int run = 0;
    for (int j = 0; j < 4; ++j) {
        int idx = idx0 + j;
        if (idx < N) row_ptr[idx] = baseoff + run;
        run += v[j];
    }
}

__global__ __launch_bounds__(256) void k_copy(const int* __restrict__ a, int* __restrict__ b, int N) {
    int i = blockIdx.x * blockDim.x + threadIdx.x;
    if (i < N) b[i] = a[i];
}

__global__ __launch_bounds__(256) void k_fill(const int* __restrict__ src, const int* __restrict__ dst,
                                              int E, int* __restrict__ cursor, int* __restrict__ col) {
    int i = blockIdx.x * blockDim.x + threadIdx.x;
    if (i < E) {
        int d = dst[i];
        int p = atomicAdd(&cursor[d], 1);
        col[p] = src[i];
    }
}

// ---------------- per-layer compute ----------------

// Y[v] = dinv[v] * (X[v] @ W).  Wave-per-row; W staged in LDS; x-row broadcast via shfl.
// Safe in-place (X == Y): each row is read (one coalesced load) before its write, by one wave only.
__global__ __launch_bounds__(256) void k_gemm(const float* __restrict__ X, const float* __restrict__ W,
                                              const float* __restrict__ dinv, float* __restrict__ Y,
                                              int N, int rows_per_wave) {
    __shared__ float Ws[DIM * DIM];
    int t = threadIdx.x;
    for (int j = t; j < DIM * DIM; j += 256) Ws[j] = W[j];
    __syncthreads();
    int lane = t & 63;
    int wave = t >> 6;
    int rowStart = (blockIdx.x * 4 + wave) * rows_per_wave;
    for (int r = 0; r < rows_per_wave; ++r) {
        int row = rowStart + r;
        if (row >= N) return;
        float xv = X[row * DIM + lane];
        float acc = 0.f;
#pragma unroll
        for (int k = 0; k < DIM; ++k) {
            float xk = __shfl(xv, k, 64);
            acc = fmaf(xk, Ws[k * DIM + lane], acc);
        }
        Y[row * DIM + lane] = acc * dinv[row];
    }
}

// Out[v] = act( dinv[v] * (sum_{u in CSR[v]} Y[u] + Y[v]) + bias )
template <bool RELU>
__global__ __launch_bounds__(256) void k_agg(const float* __restrict__ Y,
                                             const int* __restrict__ row_ptr,
                                             const int* __restrict__ col,
                                             const float* __restrict__ dinv,
                                             const float* __restrict__ bias,
                                             float* __restrict__ Out, int N) {
    int t = threadIdx.x;
    int lane = t & 63;
    int v = blockIdx.x * 4 + (t >> 6);
    if (v >= N) return;
    float acc = Y[v * DIM + lane];  // self-loop term (dinv[v] factor applied below)
    int e0 = row_ptr[v], e1 = row_ptr[v + 1];
    int e = e0;
    while (e < e1) {
        int m = e1 - e; if (m > 64) m = 64;
        int u_lane = (lane < m) ? col[e + lane] : 0;
        for (int j = 0; j < m; ++j) {
            int u = __shfl(u_lane, j, 64);
            acc += Y[u * DIM + lane];
        }
        e += m;
    }
    float o = acc * dinv[v] + bias[lane];
    if (RELU) o = fmaxf(o, 0.f);
    Out[v * DIM + lane] = o;
}

// ---------------- pooling + head ----------------

__global__ __launch_bounds__(64) void k_pool(const float* __restrict__ H, const int* __restrict__ batch,
                                             int N, float* __restrict__ sums, int chunk) {
    int lane = threadIdx.x;
    int start = blockIdx.x * chunk;
    int end = start + chunk; if (end > N) end = N;
    if (start >= end) return;
    float acc = 0.f;
    int cur = batch[start];
    for (int i = start; i < end; ++i) {
        int b = batch[i];
        if (b != cur) {
            atomicAdd(&sums[cur * DIM + lane], acc);
            acc = 0.f; cur = b;
        }
        acc += H[i * DIM + lane];
    }
    atomicAdd(&sums[cur * DIM + lane], acc);
}

__global__ __launch_bounds__(64) void k_final(const float* __restrict__ sums,
                                              const int* __restrict__ batch, int N,
                                              const float* __restrict__ Wlin,
                                              const float* __restrict__ blin,
                                              float* __restrict__ out) {
    int g = blockIdx.x;
    int j = threadIdx.x;
    // count nodes in graph g via binary search on sorted batch
    int lo = 0, hi = N;
    while (lo < hi) { int mid = (lo + hi) >> 1; if (batch[mid] < g) lo = mid + 1; else hi = mid; }
    int c0 = lo;
    lo = 0; hi = N;
    int g1 = g + 1;
    while (lo < hi) { int mid = (lo + hi) >> 1; if (batch[mid] < g1) lo = mid + 1; else hi = mid; }
    int c1 = lo;
    int c = c1 - c0; if (c < 1) c = 1;
    float invc = 1.0f / (float)c;
    float acc = 0.f;
#pragma unroll
    for (int k = 0; k < DIM; ++k)
        acc = fmaf(sums[g * DIM + k] * invc, Wlin[k * DIM + j], acc);
    out[g * DIM + j] = acc + blin[j];
}

// ---------------- launch ----------------

extern "C" void kernel_launch(void* const* d_in, const int* in_sizes, int n_in,
                              void* d_out, int out_size, void* d_ws, size_t ws_size,
                              hipStream_t stream) {
    const float* x    = (const float*)d_in[0];
    const int*   edge = (const int*)d_in[1];
    const int*   batch= (const int*)d_in[2];
    const float* W1 = (const float*)d_in[3];
    const float* b1 = (const float*)d_in[4];
    const float* W2 = (const float*)d_in[5];
    const float* b2 = (const float*)d_in[6];
    const float* W3 = (const float*)d_in[7];
    const float* b3 = (const float*)d_in[8];
    const float* Wlin = (const float*)d_in[9];
    const float* blin = (const float*)d_in[10];
    float* out = (float*)d_out;

    int N = in_sizes[0] / DIM;
    int E = in_sizes[1] / 2;
    int G = out_size / DIM;
    const int* srcv = edge;
    const int* dstv = edge + E;

    char* ws = (char*)d_ws;
    auto alloc = [&](size_t bytes) {
        char* p = ws;
        ws += (bytes + 255) & ~(size_t)255;
        return p;
    };
    int nblk_scan = (N + SCAN_CHUNK - 1) / SCAN_CHUNK;
    int*   cnt     = (int*)alloc((size_t)N * 4);
    int*   row_ptr = (int*)alloc(((size_t)N + 1) * 4);
    int*   cursor  = (int*)alloc((size_t)N * 4);
    int*   colv    = (int*)alloc((size_t)E * 4);
    int*   partial = (int*)alloc((size_t)nblk_scan * 4);
    float* dinv    = (float*)alloc((size_t)N * 4);
    float* buf0    = (float*)alloc((size_t)N * DIM * 4);
    float* buf1    = (float*)alloc((size_t)N * DIM * 4);
    float* sums    = (float*)alloc((size_t)G * DIM * 4);

    hipMemsetAsync(cnt, 0, (size_t)N * 4, stream);
    hipMemsetAsync(sums, 0, (size_t)G * DIM * 4, stream);

    // CSR build (once; shared by all 3 layers)
    k_count<<<(E + 255) / 256, 256, 0, stream>>>(dstv, E, cnt);
    k_dinv<<<(N + 255) / 256, 256, 0, stream>>>(cnt, N, dinv);
    k_scan1<<<nblk_scan, 256, 0, stream>>>(cnt, N, partial);
    k_scan2<<<1, 64, 0, stream>>>(partial, nblk_scan, row_ptr, N, E);
    k_scan3<<<nblk_scan, 256, 0, stream>>>(cnt, N, partial, row_ptr);
    k_copy<<<(N + 255) / 256, 256, 0, stream>>>(row_ptr, cursor, N);
    k_fill<<<(E + 255) / 256, 256, 0, stream>>>(srcv, dstv, E, cursor, colv);

    const int RPW = 8;
    int gemmBlocks = (N + 4 * RPW - 1) / (4 * RPW);
    int aggBlocks = (N + 3) / 4;

    // Layer 1: y1 = dinv*(x@W1) -> buf0 ; h1 = relu(agg(y1)) -> buf1
    k_gemm<<<gemmBlocks, 256, 0, stream>>>(x, W1, dinv, buf0, N, RPW);
    k_agg<true><<<aggBlocks, 256, 0, stream>>>(buf0, row_ptr, colv, dinv, b1, buf1, N);
    // Layer 2: in-place gemm on buf1 ; h2 -> buf0
    k_gemm<<<gemmBlocks, 256, 0, stream>>>(buf1, W2, dinv, buf1, N, RPW);
    k_agg<true><<<aggBlocks, 256, 0, stream>>>(buf1, row_ptr, colv, dinv, b2, buf0, N);
    // Layer 3: in-place gemm on buf0 ; h3 -> buf1 (no relu)
    k_gemm<<<gemmBlocks, 256, 0, stream>>>(buf0, W3, dinv, buf0, N, RPW);
    k_agg<false><<<aggBlocks, 256, 0, stream>>>(buf0, row_ptr, colv, dinv, b3, buf1, N);

    // Global mean pool + linear head
    int chunk = 128;
    k_pool<<<(N + chunk - 1) / chunk, 64, 0, stream>>>(buf1, batch, N, sums, chunk);
    k_final<<<G, 64, 0, stream>>>(sums, batch, N, Wlin, blin, out);
}

// Round 2
// 660.952 us; speedup vs baseline: 1.4337x; 1.4337x over previous
//
#include <hip/hip_runtime.h>

#define DIM 64
#define SCAN_CHUNK 1024
#define NPW 16  // nodes per wave in k_layer

// ---------------- CSR build ----------------

__global__ __launch_bounds__(256) void k_count(const int* __restrict__ dst, int E,
                                               int* __restrict__ cnt) {
    int i = blockIdx.x * blockDim.x + threadIdx.x;
    if (i < E) atomicAdd(&cnt[dst[i]], 1);
}

// dinv[v] = rsqrt(deg+1); Xs[v,:] = x[v,:] * dinv[v]
__global__ __launch_bounds__(256) void k_prep(const int* __restrict__ cnt, const float* __restrict__ x,
                                              int N, float* __restrict__ dinv, float* __restrict__ Xs) {
    int t = threadIdx.x;
    int lane = t & 63;
    int v = blockIdx.x * 4 + (t >> 6);
    if (v >= N) return;
    float dv = rsqrtf((float)(cnt[v] + 1));
    if (lane == 0) dinv[v] = dv;
    Xs[v * DIM + lane] = x[v * DIM + lane] * dv;
}

__global__ __launch_bounds__(256) void k_scan1(const int* __restrict__ cnt, int N,
                                               int* __restrict__ partial) {
    __shared__ int sdata[256];
    int base = blockIdx.x * SCAN_CHUNK;
    int t = threadIdx.x;
    int s = 0;
    for (int j = 0; j < 4; ++j) {
        int idx = base + t + j * 256;
        if (idx < N) s += cnt[idx];
    }
    sdata[t] = s;
    __syncthreads();
    for (int off = 128; off > 0; off >>= 1) {
        if (t < off) sdata[t] += sdata[t + off];
        __syncthreads();
    }
    if (t == 0) partial[blockIdx.x] = sdata[0];
}

__global__ void k_scan2(int* __restrict__ partial, int nblk,
                        int* __restrict__ row_ptr, int N, int E) {
    if (threadIdx.x == 0) {
        int run = 0;
        for (int i = 0; i < nblk; ++i) { int v = partial[i]; partial[i] = run; run += v; }
        row_ptr[N] = E;
    }
}

__global__ __launch_bounds__(256) void k_scan3(const int* __restrict__ cnt, int N,
                                               const int* __restrict__ partial,
                                               int* __restrict__ row_ptr,
                                               int* __restrict__ cursor) {
    __shared__ int sdata[256];
    int base = blockIdx.x * SCAN_CHUNK;
    int t = threadIdx.x;
    int idx0 = base + t * 4;
    int v[4]; int s = 0;
    for (int j = 0; j < 4; ++j) { int idx = idx0 + j; v[j] = (idx < N) ? cnt[idx] : 0; s += v[j]; }
    sdata[t] = s;
    __syncthreads();
    for (int off = 1; off < 256; off <<= 1) {
        int tmp = (t >= off) ? sdata[t - off] : 0;
        __syncthreads();
        if (t >= off) sdata[t] += tmp;
        __syncthreads();
    }
    int excl = sdata[t] - s;
    int baseoff = partial[blockIdx.x] + excl;
    int run = 0;
    for (int j = 0; j < 4; ++j) {
        int idx = idx0 + j;
        if (idx < N) { row_ptr[idx] = baseoff + run; cursor[idx] = baseoff + run; }
        run += v[j];
    }
}

__global__ __launch_bounds__(256) void k_fill(const int* __restrict__ src, const int* __restrict__ dst,
                                              int E, int* __restrict__ cursor, int* __restrict__ col) {
    int i = blockIdx.x * blockDim.x + threadIdx.x;
    if (i < E) {
        int d = dst[i];
        int p = atomicAdd(&cursor[d], 1);
        col[p] = src[i];
    }
}

// ---------------- fused layer: gather(dinv-scaled rows) -> @W -> +b -> (relu) -> (scale) ----------------
// In[u] must already be dinv[u]-scaled. Computes per node v:
//   z = In[v] + sum_{u in CSR[v]} In[u]            (float4-quad gather, 4 rows/wave-instr)
//   h = dinv[v] * (z @ W) + b
//   Out[v] = SCALE_OUT ? dinv[v]*act(h) : act(h)
template <bool RELU, bool SCALE_OUT>
__global__ __launch_bounds__(256, 4) void k_layer(const float* __restrict__ In,
                                                  const int* __restrict__ row_ptr,
                                                  const int* __restrict__ col,
                                                  const float* __restrict__ dinv,
                                                  const float* __restrict__ W,
                                                  const float* __restrict__ bias,
                                                  float* __restrict__ Out, int N) {
    int t = threadIdx.x;
    int lane = t & 63;
    int wave = t >> 6;
    int g = lane >> 4;    // quad group 0..3
    int gl = lane & 15;   // lane within group: covers float4 #gl of a row

    // W column `lane` in registers
    float wreg[DIM];
#pragma unroll
    for (int k = 0; k < DIM; ++k) wreg[k] = W[k * DIM + lane];
    float blane = bias[lane];

    const float4* InR = (const float4*)In;  // 16 float4 per row

    int v0 = (blockIdx.x * 4 + wave) * NPW;
    for (int r = 0; r < NPW; ++r) {
        int v = v0 + r;
        if (v >= N) return;
        int e0 = row_ptr[v];
        int e1 = row_ptr[v + 1];
        int d1 = e1 - e0 + 1;  // neighbors + self
        float4 accA = make_float4(0.f, 0.f, 0.f, 0.f);
        float4 accB = make_float4(0.f, 0.f, 0.f, 0.f);
        int base = 0;
        while (base < d1) {
            int m = d1 - base; if (m > 64) m = 64;
            // slot list: slot 0 = self, slots 1.. = neighbors
            int slot = base + lane;
            int u = v;
            if (slot > 0 && slot < d1) u = col[e0 + slot - 1];
            int nfull = m >> 2;
            int rem = m & 3;
            int q = 0;
            for (; q + 2 <= nfull; q += 2) {
                int u0 = __shfl(u, q * 4 + g, 64);
                int u1 = __shfl(u, q * 4 + 4 + g, 64);
                float4 a0 = InR[u0 * 16 + gl];
                float4 a1 = InR[u1 * 16 + gl];
                accA.x += a0.x; accA.y += a0.y; accA.z += a0.z; accA.w += a0.w;
                accB.x += a1.x; accB.y += a1.y; accB.z += a1.z; accB.w += a1.w;
            }
            for (; q < nfull; ++q) {
                int u0 = __shfl(u, q * 4 + g, 64);
                float4 a0 = InR[u0 * 16 + gl];
                accA.x += a0.x; accA.y += a0.y; accA.z += a0.z; accA.w += a0.w;
            }
            if (rem) {
                int sidx = nfull * 4 + g;
                bool ok = sidx < m;
                int uu = __shfl(u, ok ? sidx : 0, 64);
                float4 a0 = InR[uu * 16 + gl];
                if (ok) { accA.x += a0.x; accA.y += a0.y; accA.z += a0.z; accA.w += a0.w; }
            }
            base += m;
        }
        float4 z;
        z.x = accA.x + accB.x; z.y = accA.y + accB.y;
        z.z = accA.z + accB.z; z.w = accA.w + accB.w;
        // reduce across the 4 groups: after this every lane holds full z for features [4*gl..4*gl+3]
        z.x += __shfl_xor(z.x, 16, 64); z.y += __shfl_xor(z.y, 16, 64);
        z.z += __shfl_xor(z.z, 16, 64); z.w += __shfl_xor(z.w, 16, 64);
        z.x += __shfl_xor(z.x, 32, 64); z.y += __shfl_xor(z.y, 32, 64);
        z.z += __shfl_xor(z.z, 32, 64); z.w += __shfl_xor(z.w, 32, 64);
        float za[4] = {z.x, z.y, z.z, z.w};
        // out[lane] = dinv[v]*(z @ W)[lane] + b[lane]; z[k] lives in lane (k>>2) component (k&3)
        float rdot = 0.f;
#pragma unroll
        for (int k = 0; k < DIM; ++k) {
            float zk = __shfl(za[k & 3], k >> 2, 64);
            rdot = fmaf(zk, wreg[k], rdot);
        }
        float dv = dinv[v];
        float h = fmaf(dv, rdot, blane);
        if (RELU) h = fmaxf(h, 0.f);
        if (SCALE_OUT) h *= dv;
        Out[v * DIM + lane] = h;
    }
}

// ---------------- pooling + head ----------------

__global__ __launch_bounds__(256) void k_pool(const float* __restrict__ H, const int* __restrict__ batch,
                                              int N, float* __restrict__ sums, int chunk) {
    int t = threadIdx.x;
    int lane = t & 63;
    int start = (blockIdx.x * 4 + (t >> 6)) * chunk;
    int end = start + chunk; if (end > N) end = N;
    if (start >= end) return;
    float acc = 0.f;
    int cur = batch[start];
    for (int i = start; i < end; ++i) {
        int b = batch[i];
        if (b != cur) {
            atomicAdd(&sums[cur * DIM + lane], acc);
            acc = 0.f; cur = b;
        }
        acc += H[i * DIM + lane];
    }
    atomicAdd(&sums[cur * DIM + lane], acc);
}

__global__ __launch_bounds__(64) void k_final(const float* __restrict__ sums,
                                              const int* __restrict__ batch, int N,
                                              const float* __restrict__ Wlin,
                                              const float* __restrict__ blin,
                                              float* __restrict__ out) {
    int g = blockIdx.x;
    int j = threadIdx.x;
    int lo = 0, hi = N;
    while (lo < hi) { int mid = (lo + hi) >> 1; if (batch[mid] < g) lo = mid + 1; else hi = mid; }
    int c0 = lo;
    lo = 0; hi = N;
    int g1 = g + 1;
    while (lo < hi) { int mid = (lo + hi) >> 1; if (batch[mid] < g1) lo = mid + 1; else hi = mid; }
    int c1 = lo;
    int c = c1 - c0; if (c < 1) c = 1;
    float invc = 1.0f / (float)c;
    float acc = 0.f;
#pragma unroll
    for (int k = 0; k < DIM; ++k)
        acc = fmaf(sums[g * DIM + k] * invc, Wlin[k * DIM + j], acc);
    out[g * DIM + j] = acc + blin[j];
}

// ---------------- launch ----------------

extern "C" void kernel_launch(void* const* d_in, const int* in_sizes, int n_in,
                              void* d_out, int out_size, void* d_ws, size_t ws_size,
                              hipStream_t stream) {
    const float* x    = (const float*)d_in[0];
    const int*   edge = (const int*)d_in[1];
    const int*   batch= (const int*)d_in[2];
    const float* W1 = (const float*)d_in[3];
    const float* b1 = (const float*)d_in[4];
    const float* W2 = (const float*)d_in[5];
    const float* b2 = (const float*)d_in[6];
    const float* W3 = (const float*)d_in[7];
    const float* b3 = (const float*)d_in[8];
    const float* Wlin = (const float*)d_in[9];
    const float* blin = (const float*)d_in[10];
    float* out = (float*)d_out;

    int N = in_sizes[0] / DIM;
    int E = in_sizes[1] / 2;
    int G = out_size / DIM;
    const int* srcv = edge;
    const int* dstv = edge + E;

    char* ws = (char*)d_ws;
    auto alloc = [&](size_t bytes) {
        char* p = ws;
        ws += (bytes + 255) & ~(size_t)255;
        return p;
    };
    int nblk_scan = (N + SCAN_CHUNK - 1) / SCAN_CHUNK;
    int*   cnt     = (int*)alloc((size_t)N * 4);
    int*   row_ptr = (int*)alloc(((size_t)N + 1) * 4);
    int*   cursor  = (int*)alloc((size_t)N * 4);
    int*   colv    = (int*)alloc((size_t)E * 4);
    int*   partial = (int*)alloc((size_t)nblk_scan * 4);
    float* dinv    = (float*)alloc((size_t)N * 4);
    float* Xs      = (float*)alloc((size_t)N * DIM * 4);
    float* buf0    = (float*)alloc((size_t)N * DIM * 4);
    float* buf1    = (float*)alloc((size_t)N * DIM * 4);
    float* sums    = (float*)alloc((size_t)G * DIM * 4);

    hipMemsetAsync(cnt, 0, (size_t)N * 4, stream);
    hipMemsetAsync(sums, 0, (size_t)G * DIM * 4, stream);

    // CSR build (once; shared by all 3 layers)
    k_count<<<(E + 255) / 256, 256, 0, stream>>>(dstv, E, cnt);
    k_prep<<<(N + 3) / 4, 256, 0, stream>>>(cnt, x, N, dinv, Xs);
    k_scan1<<<nblk_scan, 256, 0, stream>>>(cnt, N, partial);
    k_scan2<<<1, 64, 0, stream>>>(partial, nblk_scan, row_ptr, N, E);
    k_scan3<<<nblk_scan, 256, 0, stream>>>(cnt, N, partial, row_ptr, cursor);
    k_fill<<<(E + 255) / 256, 256, 0, stream>>>(srcv, dstv, E, cursor, colv);

    int layerBlocks = (N + 4 * NPW - 1) / (4 * NPW);

    // Layer 1: gather Xs -> Hs1 (buf0, scaled for next gather)
    k_layer<true, true><<<layerBlocks, 256, 0, stream>>>(Xs, row_ptr, colv, dinv, W1, b1, buf0, N);
    // Layer 2: gather buf0 -> Hs2 (buf1, scaled)
    k_layer<true, true><<<layerBlocks, 256, 0, stream>>>(buf0, row_ptr, colv, dinv, W2, b2, buf1, N);
    // Layer 3: gather buf1 -> H3 (buf0, UNscaled, no relu) for pooling
    k_layer<false, false><<<layerBlocks, 256, 0, stream>>>(buf1, row_ptr, colv, dinv, W3, b3, buf0, N);

    // Global mean pool + linear head
    int chunk = 64;
    int poolBlocks = (N + 4 * chunk - 1) / (4 * chunk);
    k_pool<<<poolBlocks, 256, 0, stream>>>(buf0, batch, N, sums, chunk);
    k_final<<<G, 64, 0, stream>>>(sums, batch, N, Wlin, blin, out);
}

// Round 3
// 517.733 us; speedup vs baseline: 1.8303x; 1.2766x over previous
//
#include <hip/hip_runtime.h>

#define DIM 64
#define NPW 16        // nodes per wave in k_layer
#define NB_SHIFT 8    // 256 nodes per bucket
#define NB 256
#define BMAX 1024     // max buckets supported (N <= 262144)
#define TILE 4096     // edges per binB block
#define EPT 16        // TILE / 256

// ---------------- bucketed CSR build ----------------

// Pass A: count edges per destination bucket (LDS-aggregated).
__global__ __launch_bounds__(256) void k_binA(const int* __restrict__ dst, int E, int B,
                                              int* __restrict__ bucketCnt) {
    __shared__ int cntL[BMAX];
    int t = threadIdx.x;
    for (int j = t; j < B; j += 256) cntL[j] = 0;
    __syncthreads();
    int stride = gridDim.x * 256;
    for (int i = blockIdx.x * 256 + t; i < E; i += stride)
        atomicAdd(&cntL[dst[i] >> NB_SHIFT], 1);
    __syncthreads();
    for (int j = t; j < B; j += 256)
        if (cntL[j]) atomicAdd(&bucketCnt[j], cntL[j]);
}

// Pass A2: exclusive scan of bucket counts (one block, 256 threads, 2 elems each).
__global__ __launch_bounds__(256) void k_scanB(const int* __restrict__ bucketCnt, int B, int E, int N,
                                               int* __restrict__ bucketOff,
                                               int* __restrict__ bucketCursor,
                                               int* __restrict__ row_ptr) {
    __shared__ int sdata[256];
    int t = threadIdx.x;
    int i0 = 2 * t, i1 = 2 * t + 1;
    int a0 = (i0 < B) ? bucketCnt[i0] : 0;
    int a1 = (i1 < B) ? bucketCnt[i1] : 0;
    int s = a0 + a1;
    sdata[t] = s;
    __syncthreads();
    for (int off = 1; off < 256; off <<= 1) {
        int tmp = (t >= off) ? sdata[t - off] : 0;
        __syncthreads();
        if (t >= off) sdata[t] += tmp;
        __syncthreads();
    }
    int excl = sdata[t] - s;
    if (i0 <= B) { bucketOff[i0] = excl; if (i0 < B) bucketCursor[i0] = excl; }
    int o1 = excl + a0;
    if (i1 <= B) { bucketOff[i1] = o1; if (i1 < B) bucketCursor[i1] = o1; }
    if (t == 0) row_ptr[N] = E;
}

// Pass B: scatter packed edges (localNode<<17 | src) into bucket-contiguous regions.
// Per-tile LDS counting -> one global reservation per (tile,bucket) -> sequential appends.
__global__ __launch_bounds__(256) void k_binB(const int* __restrict__ src, const int* __restrict__ dst,
                                              int E, int B, int* __restrict__ bucketCursor,
                                              int* __restrict__ pairs) {
    __shared__ int cntL[BMAX];
    __shared__ int baseL[BMAX];
    int t = threadIdx.x;
    for (int j = t; j < B; j += 256) cntL[j] = 0;
    __syncthreads();
    int tile0 = blockIdx.x * TILE;
    int s_[EPT], d_[EPT], o_[EPT];
#pragma unroll
    for (int j = 0; j < EPT; ++j) {
        int i = tile0 + j * 256 + t;
        if (i < E) {
            s_[j] = src[i];
            d_[j] = dst[i];
            o_[j] = atomicAdd(&cntL[d_[j] >> NB_SHIFT], 1);
        } else {
            d_[j] = -1;
        }
    }
    __syncthreads();
    for (int j = t; j < B; j += 256)
        if (cntL[j]) baseL[j] = atomicAdd(&bucketCursor[j], cntL[j]);
    __syncthreads();
#pragma unroll
    for (int j = 0; j < EPT; ++j) {
        if (d_[j] >= 0) {
            int b = d_[j] >> NB_SHIFT;
            pairs[baseL[b] + o_[j]] = ((d_[j] & (NB - 1)) << 17) | s_[j];
        }
    }
}

// Pass C: per-bucket local CSR build entirely in LDS; also emits row_ptr and dinv.
__global__ __launch_bounds__(256) void k_buildCSR(const int* __restrict__ pairs,
                                                  const int* __restrict__ bucketOff,
                                                  int N, int* __restrict__ row_ptr,
                                                  int* __restrict__ col,
                                                  float* __restrict__ dinv) {
    __shared__ int cntL[NB];
    __shared__ int sdata[NB];
    __shared__ int curL[NB];
    int t = threadIdx.x;
    int b = blockIdx.x;
    int nodeBase = b << NB_SHIFT;
    int nNodes = N - nodeBase; if (nNodes > NB) nNodes = NB;
    int e0 = bucketOff[b], e1 = bucketOff[b + 1];
    cntL[t] = 0;
    __syncthreads();
    for (int i = e0 + t; i < e1; i += 256)
        atomicAdd(&cntL[pairs[i] >> 17], 1);
    __syncthreads();
    int c = cntL[t];
    sdata[t] = c;
    __syncthreads();
    for (int off = 1; off < 256; off <<= 1) {
        int tmp = (t >= off) ? sdata[t - off] : 0;
        __syncthreads();
        if (t >= off) sdata[t] += tmp;
        __syncthreads();
    }
    int excl = sdata[t] - c;
    if (t < nNodes) {
        row_ptr[nodeBase + t] = e0 + excl;
        dinv[nodeBase + t] = rsqrtf((float)(c + 1));
    }
    curL[t] = excl;
    __syncthreads();
    for (int i = e0 + t; i < e1; i += 256) {
        int p = pairs[i];
        int l = p >> 17;
        int slot = atomicAdd(&curL[l], 1);
        col[e0 + slot] = p & 0x1FFFF;
    }
}

// Xs[v,:] = x[v,:] * dinv[v]
__global__ __launch_bounds__(256) void k_prep(const float* __restrict__ dinv, const float* __restrict__ x,
                                              int N, float* __restrict__ Xs) {
    int t = threadIdx.x;
    int lane = t & 63;
    int v = blockIdx.x * 4 + (t >> 6);
    if (v >= N) return;
    Xs[v * DIM + lane] = x[v * DIM + lane] * dinv[v];
}

// ---------------- fused layer: gather(dinv-scaled rows) -> @W -> +b -> (relu) -> (scale) ----------------
template <bool RELU, bool SCALE_OUT>
__global__ __launch_bounds__(256, 4) void k_layer(const float* __restrict__ In,
                                                  const int* __restrict__ row_ptr,
                                                  const int* __restrict__ col,
                                                  const float* __restrict__ dinv,
                                                  const float* __restrict__ W,
                                                  const float* __restrict__ bias,
                                                  float* __restrict__ Out, int N) {
    int t = threadIdx.x;
    int lane = t & 63;
    int wave = t >> 6;
    int g = lane >> 4;    // quad group 0..3
    int gl = lane & 15;   // float4 index within a row

    float wreg[DIM];
#pragma unroll
    for (int k = 0; k < DIM; ++k) wreg[k] = W[k * DIM + lane];
    float blane = bias[lane];

    const float4* InR = (const float4*)In;  // 16 float4 per row

    int v0 = (blockIdx.x * 4 + wave) * NPW;
    for (int r = 0; r < NPW; ++r) {
        int v = v0 + r;
        if (v >= N) return;
        int e0 = row_ptr[v];
        int e1 = row_ptr[v + 1];
        int d1 = e1 - e0 + 1;  // neighbors + self
        float4 accA = make_float4(0.f, 0.f, 0.f, 0.f);
        float4 accB = make_float4(0.f, 0.f, 0.f, 0.f);
        int base = 0;
        while (base < d1) {
            int m = d1 - base; if (m > 64) m = 64;
            int slot = base + lane;
            int u = v;
            if (slot > 0 && slot < d1) u = col[e0 + slot - 1];
            int nfull = m >> 2;
            int rem = m & 3;
            int q = 0;
            for (; q + 2 <= nfull; q += 2) {
                int u0 = __shfl(u, q * 4 + g, 64);
                int u1 = __shfl(u, q * 4 + 4 + g, 64);
                float4 a0 = InR[u0 * 16 + gl];
                float4 a1 = InR[u1 * 16 + gl];
                accA.x += a0.x; accA.y += a0.y; accA.z += a0.z; accA.w += a0.w;
                accB.x += a1.x; accB.y += a1.y; accB.z += a1.z; accB.w += a1.w;
            }
            for (; q < nfull; ++q) {
                int u0 = __shfl(u, q * 4 + g, 64);
                float4 a0 = InR[u0 * 16 + gl];
                accA.x += a0.x; accA.y += a0.y; accA.z += a0.z; accA.w += a0.w;
            }
            if (rem) {
                int sidx = nfull * 4 + g;
                bool ok = sidx < m;
                int uu = __shfl(u, ok ? sidx : 0, 64);
                float4 a0 = InR[uu * 16 + gl];
                if (ok) { accA.x += a0.x; accA.y += a0.y; accA.z += a0.z; accA.w += a0.w; }
            }
            base += m;
        }
        float4 z;
        z.x = accA.x + accB.x; z.y = accA.y + accB.y;
        z.z = accA.z + accB.z; z.w = accA.w + accB.w;
        z.x += __shfl_xor(z.x, 16, 64); z.y += __shfl_xor(z.y, 16, 64);
        z.z += __shfl_xor(z.z, 16, 64); z.w += __shfl_xor(z.w, 16, 64);
        z.x += __shfl_xor(z.x, 32, 64); z.y += __shfl_xor(z.y, 32, 64);
        z.z += __shfl_xor(z.z, 32, 64); z.w += __shfl_xor(z.w, 32, 64);
        float za[4] = {z.x, z.y, z.z, z.w};
        float rdot = 0.f;
#pragma unroll
        for (int k = 0; k < DIM; ++k) {
            float zk = __shfl(za[k & 3], k >> 2, 64);
            rdot = fmaf(zk, wreg[k], rdot);
        }
        float dv = dinv[v];
        float h = fmaf(dv, rdot, blane);
        if (RELU) h = fmaxf(h, 0.f);
        if (SCALE_OUT) h *= dv;
        Out[v * DIM + lane] = h;
    }
}

// ---------------- pooling + head ----------------

__global__ __launch_bounds__(256) void k_pool(const float* __restrict__ H, const int* __restrict__ batch,
                                              int N, float* __restrict__ sums, int chunk) {
    int t = threadIdx.x;
    int lane = t & 63;
    int start = (blockIdx.x * 4 + (t >> 6)) * chunk;
    int end = start + chunk; if (end > N) end = N;
    if (start >= end) return;
    float acc = 0.f;
    int cur = batch[start];
    for (int i = start; i < end; ++i) {
        int b = batch[i];
        if (b != cur) {
            atomicAdd(&sums[cur * DIM + lane], acc);
            acc = 0.f; cur = b;
        }
        acc += H[i * DIM + lane];
    }
    atomicAdd(&sums[cur * DIM + lane], acc);
}

__global__ __launch_bounds__(64) void k_final(const float* __restrict__ sums,
                                              const int* __restrict__ batch, int N,
                                              const float* __restrict__ Wlin,
                                              const float* __restrict__ blin,
                                              float* __restrict__ out) {
    int g = blockIdx.x;
    int j = threadIdx.x;
    int lo = 0, hi = N;
    while (lo < hi) { int mid = (lo + hi) >> 1; if (batch[mid] < g) lo = mid + 1; else hi = mid; }
    int c0 = lo;
    lo = 0; hi = N;
    int g1 = g + 1;
    while (lo < hi) { int mid = (lo + hi) >> 1; if (batch[mid] < g1) lo = mid + 1; else hi = mid; }
    int c1 = lo;
    int c = c1 - c0; if (c < 1) c = 1;
    float invc = 1.0f / (float)c;
    float acc = 0.f;
#pragma unroll
    for (int k = 0; k < DIM; ++k)
        acc = fmaf(sums[g * DIM + k] * invc, Wlin[k * DIM + j], acc);
    out[g * DIM + j] = acc + blin[j];
}

// ---------------- launch ----------------

extern "C" void kernel_launch(void* const* d_in, const int* in_sizes, int n_in,
                              void* d_out, int out_size, void* d_ws, size_t ws_size,
                              hipStream_t stream) {
    const float* x    = (const float*)d_in[0];
    const int*   edge = (const int*)d_in[1];
    const int*   batch= (const int*)d_in[2];
    const float* W1 = (const float*)d_in[3];
    const float* b1 = (const float*)d_in[4];
    const float* W2 = (const float*)d_in[5];
    const float* b2 = (const float*)d_in[6];
    const float* W3 = (const float*)d_in[7];
    const float* b3 = (const float*)d_in[8];
    const float* Wlin = (const float*)d_in[9];
    const float* blin = (const float*)d_in[10];
    float* out = (float*)d_out;

    int N = in_sizes[0] / DIM;
    int E = in_sizes[1] / 2;
    int G = out_size / DIM;
    const int* srcv = edge;
    const int* dstv = edge + E;
    int B = (N + NB - 1) >> NB_SHIFT;   // 391 buckets for N=100000

    char* ws = (char*)d_ws;
    auto alloc = [&](size_t bytes) {
        char* p = ws;
        ws += (bytes + 255) & ~(size_t)255;
        return p;
    };
    int*   bucketCnt    = (int*)alloc((size_t)B * 4);
    int*   bucketOff    = (int*)alloc((size_t)(B + 1) * 4);
    int*   bucketCursor = (int*)alloc((size_t)B * 4);
    int*   pairs        = (int*)alloc((size_t)E * 4);
    int*   row_ptr      = (int*)alloc(((size_t)N + 1) * 4);
    int*   colv         = (int*)alloc((size_t)E * 4);
    float* dinv         = (float*)alloc((size_t)N * 4);
    float* Xs           = (float*)alloc((size_t)N * DIM * 4);
    float* buf0         = (float*)alloc((size_t)N * DIM * 4);
    float* buf1         = (float*)alloc((size_t)N * DIM * 4);
    float* sums         = (float*)alloc((size_t)G * DIM * 4);

    hipMemsetAsync(bucketCnt, 0, (size_t)B * 4, stream);
    hipMemsetAsync(sums, 0, (size_t)G * DIM * 4, stream);

    // Bucketed CSR build (once; shared by all 3 layers)
    k_binA<<<512, 256, 0, stream>>>(dstv, E, B, bucketCnt);
    k_scanB<<<1, 256, 0, stream>>>(bucketCnt, B, E, N, bucketOff, bucketCursor, row_ptr);
    k_binB<<<(E + TILE - 1) / TILE, 256, 0, stream>>>(srcv, dstv, E, B, bucketCursor, pairs);
    k_buildCSR<<<B, 256, 0, stream>>>(pairs, bucketOff, N, row_ptr, colv, dinv);
    k_prep<<<(N + 3) / 4, 256, 0, stream>>>(dinv, x, N, Xs);

    int layerBlocks = (N + 4 * NPW - 1) / (4 * NPW);

    // Layer 1: gather Xs -> Hs1 (buf0, scaled for next gather)
    k_layer<true, true><<<layerBlocks, 256, 0, stream>>>(Xs, row_ptr, colv, dinv, W1, b1, buf0, N);
    // Layer 2: gather buf0 -> Hs2 (buf1, scaled)
    k_layer<true, true><<<layerBlocks, 256, 0, stream>>>(buf0, row_ptr, colv, dinv, W2, b2, buf1, N);
    // Layer 3: gather buf1 -> H3 (buf0, UNscaled, no relu) for pooling
    k_layer<false, false><<<layerBlocks, 256, 0, stream>>>(buf1, row_ptr, colv, dinv, W3, b3, buf0, N);

    // Global mean pool + linear head
    int chunk = 64;
    int poolBlocks = (N + 4 * chunk - 1) / (4 * chunk);
    k_pool<<<poolBlocks, 256, 0, stream>>>(buf0, batch, N, sums, chunk);
    k_final<<<G, 64, 0, stream>>>(sums, batch, N, Wlin, blin, out);
}

// Round 4
// 392.489 us; speedup vs baseline: 2.4143x; 1.3191x over previous
//
#include <hip/hip_runtime.h>

#define DIM 64
#define NPW 8         // nodes per wave in k_layer
#define NB_SHIFT 8    // 256 nodes per bucket
#define NB 256
#define BMAX 1024     // max buckets supported (N <= 262144)
#define TILE 4096     // edges per binB block
#define EPT 16        // TILE / 256

// ---------------- bucketed CSR build ----------------

// Pass A: count edges per destination bucket (LDS-aggregated).
__global__ __launch_bounds__(256) void k_binA(const int* __restrict__ dst, int E, int B,
                                              int* __restrict__ bucketCnt) {
    __shared__ int cntL[BMAX];
    int t = threadIdx.x;
    for (int j = t; j < B; j += 256) cntL[j] = 0;
    __syncthreads();
    int stride = gridDim.x * 256;
    for (int i = blockIdx.x * 256 + t; i < E; i += stride)
        atomicAdd(&cntL[dst[i] >> NB_SHIFT], 1);
    __syncthreads();
    for (int j = t; j < B; j += 256)
        if (cntL[j]) atomicAdd(&bucketCnt[j], cntL[j]);
}

// Pass A2: exclusive scan of bucket counts (one block).
__global__ __launch_bounds__(256) void k_scanB(const int* __restrict__ bucketCnt, int B, int E, int N,
                                               int* __restrict__ bucketOff,
                                               int* __restrict__ bucketCursor,
                                               int* __restrict__ row_ptr) {
    __shared__ int sdata[256];
    int t = threadIdx.x;
    int i0 = 2 * t, i1 = 2 * t + 1;
    int a0 = (i0 < B) ? bucketCnt[i0] : 0;
    int a1 = (i1 < B) ? bucketCnt[i1] : 0;
    int s = a0 + a1;
    sdata[t] = s;
    __syncthreads();
    for (int off = 1; off < 256; off <<= 1) {
        int tmp = (t >= off) ? sdata[t - off] : 0;
        __syncthreads();
        if (t >= off) sdata[t] += tmp;
        __syncthreads();
    }
    int excl = sdata[t] - s;
    if (i0 <= B) { bucketOff[i0] = excl; if (i0 < B) bucketCursor[i0] = excl; }
    int o1 = excl + a0;
    if (i1 <= B) { bucketOff[i1] = o1; if (i1 < B) bucketCursor[i1] = o1; }
    if (t == 0) row_ptr[N] = E;
}

// Pass B: scatter packed edges (localNode<<17 | src) into bucket-contiguous regions.
__global__ __launch_bounds__(256) void k_binB(const int* __restrict__ src, const int* __restrict__ dst,
                                              int E, int B, int* __restrict__ bucketCursor,
                                              int* __restrict__ pairs) {
    __shared__ int cntL[BMAX];
    __shared__ int baseL[BMAX];
    int t = threadIdx.x;
    for (int j = t; j < B; j += 256) cntL[j] = 0;
    __syncthreads();
    int tile0 = blockIdx.x * TILE;
    int s_[EPT], d_[EPT], o_[EPT];
#pragma unroll
    for (int j = 0; j < EPT; ++j) {
        int i = tile0 + j * 256 + t;
        if (i < E) {
            s_[j] = src[i];
            d_[j] = dst[i];
            o_[j] = atomicAdd(&cntL[d_[j] >> NB_SHIFT], 1);
        } else {
            d_[j] = -1;
        }
    }
    __syncthreads();
    for (int j = t; j < B; j += 256)
        if (cntL[j]) baseL[j] = atomicAdd(&bucketCursor[j], cntL[j]);
    __syncthreads();
#pragma unroll
    for (int j = 0; j < EPT; ++j) {
        if (d_[j] >= 0) {
            int b = d_[j] >> NB_SHIFT;
            pairs[baseL[b] + o_[j]] = ((d_[j] & (NB - 1)) << 17) | s_[j];
        }
    }
}

// Pass C: per-bucket local CSR build in LDS; emits row_ptr, col, dinv.
__global__ __launch_bounds__(256) void k_buildCSR(const int* __restrict__ pairs,
                                                  const int* __restrict__ bucketOff,
                                                  int N, int* __restrict__ row_ptr,
                                                  int* __restrict__ col,
                                                  float* __restrict__ dinv) {
    __shared__ int cntL[NB];
    __shared__ int sdata[NB];
    __shared__ int curL[NB];
    int t = threadIdx.x;
    int b = blockIdx.x;
    int nodeBase = b << NB_SHIFT;
    int nNodes = N - nodeBase; if (nNodes > NB) nNodes = NB;
    int e0 = bucketOff[b], e1 = bucketOff[b + 1];
    cntL[t] = 0;
    __syncthreads();
    for (int i = e0 + t; i < e1; i += 256)
        atomicAdd(&cntL[pairs[i] >> 17], 1);
    __syncthreads();
    int c = cntL[t];
    sdata[t] = c;
    __syncthreads();
    for (int off = 1; off < 256; off <<= 1) {
        int tmp = (t >= off) ? sdata[t - off] : 0;
        __syncthreads();
        if (t >= off) sdata[t] += tmp;
        __syncthreads();
    }
    int excl = sdata[t] - c;
    if (t < nNodes) {
        row_ptr[nodeBase + t] = e0 + excl;
        dinv[nodeBase + t] = rsqrtf((float)(c + 1));
    }
    curL[t] = excl;
    __syncthreads();
    for (int i = e0 + t; i < e1; i += 256) {
        int p = pairs[i];
        int l = p >> 17;
        int slot = atomicAdd(&curL[l], 1);
        col[e0 + slot] = p & 0x1FFFF;
    }
}

// Xs[v,:] = x[v,:] * dinv[v]
__global__ __launch_bounds__(256) void k_prep(const float* __restrict__ dinv, const float* __restrict__ x,
                                              int N, float* __restrict__ Xs) {
    int t = threadIdx.x;
    int lane = t & 63;
    int v = blockIdx.x * 4 + (t >> 6);
    if (v >= N) return;
    Xs[v * DIM + lane] = x[v * DIM + lane] * dinv[v];
}

// ---------------- fused layer ----------------
// z = In[v] + sum_{u in CSR[v]} In[u]  (quad-group float4 gather, 4 loads in flight)
// h = dinv[v]*(z @ W) + b ; Out[v] = SCALE_OUT ? dinv*act(h) : act(h)
// W staged in LDS transposed as WL4[k16*64 + lane] = {W[4k16+j][lane]}_j ; z broadcast via per-wave LDS slot.
template <bool RELU, bool SCALE_OUT>
__global__ __launch_bounds__(256, 8) void k_layer(const float* __restrict__ In,
                                                  const int* __restrict__ row_ptr,
                                                  const int* __restrict__ col,
                                                  const float* __restrict__ dinv,
                                                  const float* __restrict__ W,
                                                  const float* __restrict__ bias,
                                                  float* __restrict__ Out, int N) {
    __shared__ float WLs[DIM * DIM];     // 16 KB, transposed-quad layout
    __shared__ float4 zL[4 * 16];        // per-wave z staging
    int t = threadIdx.x;
    int lane = t & 63;
    int wave = t >> 6;
    int g = lane >> 4;    // quad group 0..3
    int gl = lane & 15;   // float4 index within a row

    // stage W: WLs[(k>>2)*256 + lane*4 + (k&3)] = W[k*64 + lane]
    for (int k = wave; k < DIM; k += 4)
        WLs[(k >> 2) * 256 + lane * 4 + (k & 3)] = W[k * DIM + lane];
    __syncthreads();
    const float4* WL4 = (const float4*)WLs;   // WL4[k16*64 + lane]

    float blane = bias[lane];
    const float4* InR = (const float4*)In;    // 16 float4 per row

    int v0 = (blockIdx.x * 4 + wave) * NPW;
    for (int r = 0; r < NPW; ++r) {
        int v = v0 + r;
        if (v >= N) return;
        int e0 = row_ptr[v];
        int e1 = row_ptr[v + 1];
        float dv = dinv[v];
        int d1 = e1 - e0 + 1;  // neighbors + self
        float4 acc0 = make_float4(0.f, 0.f, 0.f, 0.f);
        float4 acc1 = make_float4(0.f, 0.f, 0.f, 0.f);
        float4 acc2 = make_float4(0.f, 0.f, 0.f, 0.f);
        float4 acc3 = make_float4(0.f, 0.f, 0.f, 0.f);
        int base = 0;
        while (base < d1) {
            int m = d1 - base; if (m > 64) m = 64;
            int slot = base + lane;
            int u = v;
            if (slot > 0 && slot < d1) u = col[e0 + slot - 1];
            int nfull = m >> 2;
            int q = 0;
            for (; q + 4 <= nfull; q += 4) {
                int u0 = __shfl(u, (q + 0) * 4 + g, 64);
                int u1 = __shfl(u, (q + 1) * 4 + g, 64);
                int u2 = __shfl(u, (q + 2) * 4 + g, 64);
                int u3 = __shfl(u, (q + 3) * 4 + g, 64);
                float4 a0 = InR[u0 * 16 + gl];
                float4 a1 = InR[u1 * 16 + gl];
                float4 a2 = InR[u2 * 16 + gl];
                float4 a3 = InR[u3 * 16 + gl];
                acc0.x += a0.x; acc0.y += a0.y; acc0.z += a0.z; acc0.w += a0.w;
                acc1.x += a1.x; acc1.y += a1.y; acc1.z += a1.z; acc1.w += a1.w;
                acc2.x += a2.x; acc2.y += a2.y; acc2.z += a2.z; acc2.w += a2.w;
                acc3.x += a3.x; acc3.y += a3.y; acc3.z += a3.z; acc3.w += a3.w;
            }
            for (; q + 2 <= nfull; q += 2) {
                int u0 = __shfl(u, (q + 0) * 4 + g, 64);
                int u1 = __shfl(u, (q + 1) * 4 + g, 64);
                float4 a0 = InR[u0 * 16 + gl];
                float4 a1 = InR[u1 * 16 + gl];
                acc0.x += a0.x; acc0.y += a0.y; acc0.z += a0.z; acc0.w += a0.w;
                acc1.x += a1.x; acc1.y += a1.y; acc1.z += a1.z; acc1.w += a1.w;
            }
            for (; q < nfull; ++q) {
                int u0 = __shfl(u, q * 4 + g, 64);
                float4 a0 = InR[u0 * 16 + gl];
                acc0.x += a0.x; acc0.y += a0.y; acc0.z += a0.z; acc0.w += a0.w;
            }
            if (m & 3) {
                int sidx = nfull * 4 + g;
                bool ok = sidx < m;
                int uu = __shfl(u, ok ? sidx : 0, 64);
                float4 a0 = InR[uu * 16 + gl];
                if (ok) { acc0.x += a0.x; acc0.y += a0.y; acc0.z += a0.z; acc0.w += a0.w; }
            }
            base += m;
        }
        float4 z;
        z.x = (acc0.x + acc1.x) + (acc2.x + acc3.x);
        z.y = (acc0.y + acc1.y) + (acc2.y + acc3.y);
        z.z = (acc0.z + acc1.z) + (acc2.z + acc3.z);
        z.w = (acc0.w + acc1.w) + (acc2.w + acc3.w);
        z.x += __shfl_xor(z.x, 16, 64); z.y += __shfl_xor(z.y, 16, 64);
        z.z += __shfl_xor(z.z, 16, 64); z.w += __shfl_xor(z.w, 16, 64);
        z.x += __shfl_xor(z.x, 32, 64); z.y += __shfl_xor(z.y, 32, 64);
        z.z += __shfl_xor(z.z, 32, 64); z.w += __shfl_xor(z.w, 32, 64);
        // stage z (replicated across groups; group 0 writes), intra-wave -> no barrier
        if (g == 0) zL[wave * 16 + gl] = z;
        float rdot = 0.f;
#pragma unroll
        for (int k16 = 0; k16 < 16; ++k16) {
            float4 zc = zL[wave * 16 + k16];      // broadcast read
            float4 wv = WL4[k16 * 64 + lane];
            rdot = fmaf(zc.x, wv.x, rdot);
            rdot = fmaf(zc.y, wv.y, rdot);
            rdot = fmaf(zc.z, wv.z, rdot);
            rdot = fmaf(zc.w, wv.w, rdot);
        }
        float h = fmaf(dv, rdot, blane);
        if (RELU) h = fmaxf(h, 0.f);
        if (SCALE_OUT) h *= dv;
        Out[v * DIM + lane] = h;
    }
}

// ---------------- pooling + head ----------------

__global__ __launch_bounds__(256) void k_pool(const float* __restrict__ H, const int* __restrict__ batch,
                                              int N, float* __restrict__ sums, int chunk) {
    int t = threadIdx.x;
    int lane = t & 63;
    int start = (blockIdx.x * 4 + (t >> 6)) * chunk;
    int end = start + chunk; if (end > N) end = N;
    if (start >= end) return;
    float acc = 0.f;
    int cur = batch[start];
    for (int i = start; i < end; ++i) {
        int b = batch[i];
        if (b != cur) {
            atomicAdd(&sums[cur * DIM + lane], acc);
            acc = 0.f; cur = b;
        }
        acc += H[i * DIM + lane];
    }
    atomicAdd(&sums[cur * DIM + lane], acc);
}

__global__ __launch_bounds__(64) void k_final(const float* __restrict__ sums,
                                              const int* __restrict__ batch, int N,
                                              const float* __restrict__ Wlin,
                                              const float* __restrict__ blin,
                                              float* __restrict__ out) {
    int g = blockIdx.x;
    int j = threadIdx.x;
    int lo = 0, hi = N;
    while (lo < hi) { int mid = (lo + hi) >> 1; if (batch[mid] < g) lo = mid + 1; else hi = mid; }
    int c0 = lo;
    lo = 0; hi = N;
    int g1 = g + 1;
    while (lo < hi) { int mid = (lo + hi) >> 1; if (batch[mid] < g1) lo = mid + 1; else hi = mid; }
    int c1 = lo;
    int c = c1 - c0; if (c < 1) c = 1;
    float invc = 1.0f / (float)c;
    float acc = 0.f;
#pragma unroll
    for (int k = 0; k < DIM; ++k)
        acc = fmaf(sums[g * DIM + k] * invc, Wlin[k * DIM + j], acc);
    out[g * DIM + j] = acc + blin[j];
}

// ---------------- launch ----------------

extern "C" void kernel_launch(void* const* d_in, const int* in_sizes, int n_in,
                              void* d_out, int out_size, void* d_ws, size_t ws_size,
                              hipStream_t stream) {
    const float* x    = (const float*)d_in[0];
    const int*   edge = (const int*)d_in[1];
    const int*   batch= (const int*)d_in[2];
    const float* W1 = (const float*)d_in[3];
    const float* b1 = (const float*)d_in[4];
    const float* W2 = (const float*)d_in[5];
    const float* b2 = (const float*)d_in[6];
    const float* W3 = (const float*)d_in[7];
    const float* b3 = (const float*)d_in[8];
    const float* Wlin = (const float*)d_in[9];
    const float* blin = (const float*)d_in[10];
    float* out = (float*)d_out;

    int N = in_sizes[0] / DIM;
    int E = in_sizes[1] / 2;
    int G = out_size / DIM;
    const int* srcv = edge;
    const int* dstv = edge + E;
    int B = (N + NB - 1) >> NB_SHIFT;

    char* ws = (char*)d_ws;
    auto alloc = [&](size_t bytes) {
        char* p = ws;
        ws += (bytes + 255) & ~(size_t)255;
        return p;
    };
    int*   bucketCnt    = (int*)alloc((size_t)B * 4);
    int*   bucketOff    = (int*)alloc((size_t)(B + 1) * 4);
    int*   bucketCursor = (int*)alloc((size_t)B * 4);
    int*   pairs        = (int*)alloc((size_t)E * 4);
    int*   row_ptr      = (int*)alloc(((size_t)N + 1) * 4);
    int*   colv         = (int*)alloc((size_t)E * 4);
    float* dinv         = (float*)alloc((size_t)N * 4);
    float* Xs           = (float*)alloc((size_t)N * DIM * 4);
    float* buf0         = (float*)alloc((size_t)N * DIM * 4);
    float* buf1         = (float*)alloc((size_t)N * DIM * 4);
    float* sums         = (float*)alloc((size_t)G * DIM * 4);

    hipMemsetAsync(bucketCnt, 0, (size_t)B * 4, stream);
    hipMemsetAsync(sums, 0, (size_t)G * DIM * 4, stream);

    // Bucketed CSR build (once; shared by all 3 layers)
    k_binA<<<512, 256, 0, stream>>>(dstv, E, B, bucketCnt);
    k_scanB<<<1, 256, 0, stream>>>(bucketCnt, B, E, N, bucketOff, bucketCursor, row_ptr);
    k_binB<<<(E + TILE - 1) / TILE, 256, 0, stream>>>(srcv, dstv, E, B, bucketCursor, pairs);
    k_buildCSR<<<B, 256, 0, stream>>>(pairs, bucketOff, N, row_ptr, colv, dinv);
    k_prep<<<(N + 3) / 4, 256, 0, stream>>>(dinv, x, N, Xs);

    int layerBlocks = (N + 4 * NPW - 1) / (4 * NPW);

    k_layer<true, true><<<layerBlocks, 256, 0, stream>>>(Xs, row_ptr, colv, dinv, W1, b1, buf0, N);
    k_layer<true, true><<<layerBlocks, 256, 0, stream>>>(buf0, row_ptr, colv, dinv, W2, b2, buf1, N);
    k_layer<false, false><<<layerBlocks, 256, 0, stream>>>(buf1, row_ptr, colv, dinv, W3, b3, buf0, N);

    // Global mean pool + linear head
    int chunk = 64;
    int poolBlocks = (N + 4 * chunk - 1) / (4 * chunk);
    k_pool<<<poolBlocks, 256, 0, stream>>>(buf0, batch, N, sums, chunk);
    k_final<<<G, 64, 0, stream>>>(sums, batch, N, Wlin, blin, out);
}